// Round 13
// baseline (89.230 us; speedup 1.0000x reference)
//
#include <hip/hip_runtime.h>
#include <math.h>

#define KS 21
#define K2 441
#define NB 8
#define PPI 4096
#define NPIX 65536
#define STR 72                     // LDS activation row stride (u16)
#define XW 276
#define BPX 128                    // pixels per block (2 low-res rows)
#define NTH 512                    // threads per block (8 waves)
#define XROWS 25                   // hi-res rows staged

typedef unsigned short u16;
typedef unsigned int u32;
typedef short short8v __attribute__((ext_vector_type(8)));
typedef float f32x4 __attribute__((ext_vector_type(4)));
typedef float f32x16 __attribute__((ext_vector_type(16)));

// ws layout (u16 units): layer frags 17*4096 | wout frags 28672 | bout 448 f32
#define WOUT_OFF 69632
#define BOUT_BYTE 196608

// dynamic LDS: hbuf 18432 + xs 41408 = 59840 (<64K -> 2 blocks/CU).
// sbuf/obuf alias hbuf (dead after pass-1 fragment loads).
#define LDS_HBUF  0
#define LDS_XS    18432
#define LDS_TOTAL 59840

__device__ __forceinline__ u16 f2bf(float x)
{
    union { float f; u32 u; } c; c.f = x;
    u32 r = c.u + 0x7FFF + ((c.u >> 16) & 1);
    return (u16)(r >> 16);
}
__device__ __forceinline__ float u16f(u16 h)
{ union { u32 u; float f; } c; c.u = ((u32)h) << 16; return c.f; }

// XCD-aware bijective swizzle (512 blocks): XCD x owns 64 consecutive blocks.
__device__ __forceinline__ int xcd_swz(int i)
{
    return ((i & 7) << 6) | (i >> 3);
}

// ---------------------------------------------------------------- prep ----
__global__ void prep_kernel(const float* __restrict__ w_in,
                            const float* __restrict__ rw1,
                            const float* __restrict__ rw2,
                            const float* __restrict__ w_out,
                            const float* __restrict__ b_out,
                            u16* __restrict__ wsu, float* __restrict__ bout)
{
    int idx = blockIdx.x * 256 + threadIdx.x;
    if (idx < 69632) {
        int u = idx & 4095;
        int j = u & 7, lane = (u >> 3) & 63, frag = (u >> 9) & 7;
        int kk = frag >> 2, nt = frag & 3, layer = idx >> 12;
        int i = kk * 32 + (lane >> 4) * 8 + j;      // K (input ch)
        int o = nt * 16 + (lane & 15);              // N (output ch)
        const float* src;
        if (layer == 0) src = w_in;
        else if (layer & 1) src = rw1 + ((layer - 1) >> 1) * 4096;
        else src = rw2 + ((layer - 2) >> 1) * 4096;
        wsu[idx] = f2bf(src[o * 64 + i]);
    } else if (idx < 69632 + 28672) {
        int u = idx - 69632;
        int j = u & 7, lane = (u >> 3) & 63, t6 = u >> 9;   // 0..55
        int t = t6 % 14, kk = t6 / 14;
        int tap = t * 32 + (lane & 31);
        int i = kk * 16 + (lane >> 5) * 8 + j;
        wsu[idx] = f2bf((tap < K2) ? w_out[tap * 64 + i] : 0.f);
    } else if (idx < 69632 + 28672 + 448) {
        int tap = idx - (69632 + 28672);
        bout[tap] = (tap < K2) ? b_out[tap] : -100.f;
    }
}

// ------------------------------------------------------------- fused -----
__device__ __forceinline__ int reflect256(int v)
{
    v = (v < 0) ? -v : v;
    return (v > 255) ? (510 - v) : v;
}

template <int MODE>
__device__ __forceinline__ void do_layer(u16* hb, const u16* __restrict__ wb,
                                         const float* __restrict__ bias,
                                         float* hreg, int aoff, int wbase,
                                         int c, int g, int lane)
{
    short8v a0 = *(const short8v*)(hb + aoff);
    short8v a1 = *(const short8v*)(hb + aoff + 32);
#pragma unroll
    for (int nt = 0; nt < 4; ++nt) {
        f32x4 acc = {};
        short8v b0 = *(const short8v*)(wb + ((nt)     * 64 + lane) * 8);
        short8v b1 = *(const short8v*)(wb + ((4 + nt) * 64 + lane) * 8);
        acc = __builtin_amdgcn_mfma_f32_16x16x32_bf16(a0, b0, acc, 0, 0, 0);
        acc = __builtin_amdgcn_mfma_f32_16x16x32_bf16(a1, b1, acc, 0, 0, 0);
        const float bv = bias[nt * 16 + c];
#pragma unroll
        for (int r = 0; r < 4; ++r) {
            float v = acc[r] + bv;
            if (MODE == 1) v = fmaxf(v, 0.f);
            if (MODE == 2) { v += hreg[nt * 4 + r]; hreg[nt * 4 + r] = v; }
            if (MODE == 0) hreg[nt * 4 + r] = v;
            hb[(wbase + g * 4 + r) * STR + nt * 16 + c] = f2bf(v);
        }
    }
}

__launch_bounds__(NTH, 4)
__global__ void trunk_kernel(const float* __restrict__ z,
                             const float* __restrict__ x,
                             const float* __restrict__ b_in,
                             const float* __restrict__ rb1,
                             const float* __restrict__ rb2,
                             const u16* __restrict__ wsu,
                             const float* __restrict__ bout,
                             float* __restrict__ out,
                             float* __restrict__ kout)
{
    extern __shared__ __align__(16) char smem[];
    u16*   hbuf = (u16*)(smem + LDS_HBUF);     // [128][STR]
    u16*   xs   = (u16*)(smem + LDS_XS);       // [25][3][XW]
    float* sbuf = (float*)(smem);              // [8][2][32]  (alias hbuf)
    float* obuf = (float*)(smem + 2048);       // [8][3][64]  (alias hbuf)

    const int tid = threadIdx.x, lane = tid & 63, wave = tid >> 6;  // 0..7
    const int pix0 = xcd_swz(blockIdx.x) * BPX;
    const int b = pix0 >> 12, rem0 = pix0 & 4095;
    const int hl0 = rem0 >> 6;

    // ---- stage z -> hbuf (bf16) ----
    {
        const int p = tid & 127, i0 = (tid >> 7) * 16;
        const float* zp = z + ((size_t)b * 64 + i0) * PPI + rem0 + p;
        u32* dst = (u32*)hbuf + p * (STR / 2) + i0 / 2;
#pragma unroll
        for (int i = 0; i < 16; i += 2) {
            float v0 = zp[(size_t)i * PPI];
            float v1 = zp[(size_t)(i + 1) * PPI];
            dst[i / 2] = (u32)f2bf(v0) | ((u32)f2bf(v1) << 16);
        }
    }
    // ---- stage reflected x window ----
    for (int u = tid; u < XROWS * 3 * XW; u += NTH) {
        int t = u / XW;
        int j = u - t * XW;
        int rr = t / 3, cch = t - rr * 3;
        int row = reflect256(hl0 * 4 + rr - 10);
        int xcol = reflect256(j - 10);
        xs[u] = f2bf(x[(((size_t)b * 3 + cch) * 256 + row) * 256 + xcol]);
    }
    __syncthreads();

    // ---- 17-layer trunk, wave-private rows ----
    const int c16 = lane & 15, g4 = lane >> 4;
    const int wbase = wave * 16;
    const int aoff = (wbase + c16) * STR + g4 * 8;
    float hreg[16];

    do_layer<0>(hbuf, wsu, b_in, hreg, aoff, wbase, c16, g4, lane);
#pragma unroll 1
    for (int l = 0; l < NB; ++l) {
        do_layer<1>(hbuf, wsu + (size_t)(1 + 2 * l) * 4096, rb1 + l * 64,
                    hreg, aoff, wbase, c16, g4, lane);
        do_layer<2>(hbuf, wsu + (size_t)(2 + 2 * l) * 4096, rb2 + l * 64,
                    hreg, aoff, wbase, c16, g4, lane);
    }
    __syncthreads();   // all h rows final

    // ---- wave roles: q = px-pair (64 px), s/par = tile subset ----
    const int c32 = lane & 31, hi2 = lane >> 5;
    const int q   = wave >> 2;                 // px base 64*q
    const int s   = (wave >> 1) & 1;
    const int par = wave & 1;
    const int t0  = par * 7 + (s ? 4 : 0);
    const int ntile = s ? 3 : 4;

    short8v bhA[4], bhB[4];                    // B-frags for px [64q,64q+32), [+32,+64)
#pragma unroll
    for (int kk = 0; kk < 4; ++kk) {
        bhA[kk] = *(const short8v*)(hbuf + (64 * q + c32) * STR + kk * 16 + hi2 * 8);
        bhB[kk] = *(const short8v*)(hbuf + (64 * q + 32 + c32) * STR + kk * 16 + hi2 * 8);
    }
    __syncthreads();   // hbuf dead -> sbuf/obuf aliases safe

    const u16* wob = wsu + WOUT_OFF;

    // ---- phase 1: softmax denominators (no epack cache; recompute later) ----
    float ssA = 0.f, ssB = 0.f;
#pragma unroll
    for (int ti = 0; ti < 4; ++ti) if (ti < ntile) {
        const int t = t0 + ti;
        f32x16 accA = {}, accB = {};
#pragma unroll
        for (int kk = 0; kk < 4; ++kk) {
            short8v aw = *(const short8v*)(wob + ((kk * 14 + t) * 64 + lane) * 8);
            accA = __builtin_amdgcn_mfma_f32_32x32x16_bf16(aw, bhA[kk], accA, 0, 0, 0);
            accB = __builtin_amdgcn_mfma_f32_32x32x16_bf16(aw, bhB[kk], accB, 0, 0, 0);
        }
#pragma unroll
        for (int rr = 0; rr < 8; ++rr) {
            const int r0 = 2 * rr;
            const int tap0 = t * 32 + (r0 & 3) + 8 * (r0 >> 2) + 4 * hi2;
            ssA += __expf(accA[r0] + bout[tap0]) + __expf(accA[r0 + 1] + bout[tap0 + 1]);
            ssB += __expf(accB[r0] + bout[tap0]) + __expf(accB[r0 + 1] + bout[tap0 + 1]);
        }
    }
    ssA += __shfl_xor(ssA, 32);                // both tap-halves
    ssB += __shfl_xor(ssB, 32);
    if (lane < 32) sbuf[(wave * 2 + 0) * 32 + lane] = ssA;
    else           sbuf[(wave * 2 + 1) * 32 + (lane & 31)] = ssB;
    __syncthreads();
    float ssum = 0.f;
#pragma unroll
    for (int j = 0; j < 4; ++j)
        ssum += sbuf[((4 * q + j) * 2 + hi2) * 32 + c32];
    const float inv_s = 1.f / ssum;

    // ---- phase 2: recompute, swap halves -> full 256B-granule stores + apply
    // lane's px = 64*q + lane; wl = lane, hlr = q.
    float* kb = kout + (size_t)b * K2 * PPI + rem0 + 64 * q + lane;
    float oacc0 = 0.f, oacc1 = 0.f, oacc2 = 0.f;
    const int xrb = 4 * q;
    const u16* xcb = xs + lane * 4;

#pragma unroll
    for (int ti = 0; ti < 4; ++ti) if (ti < ntile) {
        const int t = t0 + ti;
        f32x16 accA = {}, accB = {};
#pragma unroll
        for (int kk = 0; kk < 4; ++kk) {
            short8v aw = *(const short8v*)(wob + ((kk * 14 + t) * 64 + lane) * 8);
            accA = __builtin_amdgcn_mfma_f32_32x32x16_bf16(aw, bhA[kk], accA, 0, 0, 0);
            accB = __builtin_amdgcn_mfma_f32_32x32x16_bf16(aw, bhB[kk], accB, 0, 0, 0);
        }
        int tapb = t * 32;
        int ky0 = tapb / KS, kx0 = tapb - ky0 * KS;
#pragma unroll
        for (int rr = 0; rr < 8; ++rr) {
            const int r0 = 2 * rr;
            const int tap0 = tapb + 4 * hi2;
            const float eA0 = __expf(accA[r0] + bout[tap0]);
            const float eA1 = __expf(accA[r0 + 1] + bout[tap0 + 1]);
            const float eB0 = __expf(accB[r0] + bout[tap0]);
            const float eB1 = __expf(accB[r0 + 1] + bout[tap0 + 1]);
            // glue halves: {A.lo,B.lo} = tap tapb (px 0..63), {A.hi,B.hi} = tapb+4
            const float a0s = __shfl_xor(eA0, 32), b0s = __shfl_xor(eB0, 32);
            const float a1s = __shfl_xor(eA1, 32), b1s = __shfl_xor(eB1, 32);
            const bool lo = (lane < 32);
            const float pv0 = (lo ? eA0 : b0s) * inv_s;   // tap tapb
            const float pv1 = (lo ? eA1 : b1s) * inv_s;   // tap tapb+1
            const float pv4 = (lo ? a0s : eB0) * inv_s;   // tap tapb+4
            const float pv5 = (lo ? a1s : eB1) * inv_s;   // tap tapb+5
            {
                const int T = tapb;
                if (T < K2) {
                    kb[(size_t)T * PPI] = pv0;
                    const u16* xp = xcb + ((xrb + ky0) * 3) * XW + kx0;
                    oacc0 = fmaf(pv0, u16f(xp[0]), oacc0);
                    oacc1 = fmaf(pv0, u16f(xp[XW]), oacc1);
                    oacc2 = fmaf(pv0, u16f(xp[2 * XW]), oacc2);
                }
            }
            {
                const int T = tapb + 1;
                if (T < K2) {
                    int kx = kx0 + 1, ky = ky0;
                    if (kx >= KS) { kx -= KS; ++ky; }
                    kb[(size_t)T * PPI] = pv1;
                    const u16* xp = xcb + ((xrb + ky) * 3) * XW + kx;
                    oacc0 = fmaf(pv1, u16f(xp[0]), oacc0);
                    oacc1 = fmaf(pv1, u16f(xp[XW]), oacc1);
                    oacc2 = fmaf(pv1, u16f(xp[2 * XW]), oacc2);
                }
            }
            {
                const int T = tapb + 4;
                if (T < K2) {
                    int kx = kx0 + 4, ky = ky0;
                    if (kx >= KS) { kx -= KS; ++ky; }
                    kb[(size_t)T * PPI] = pv4;
                    const u16* xp = xcb + ((xrb + ky) * 3) * XW + kx;
                    oacc0 = fmaf(pv4, u16f(xp[0]), oacc0);
                    oacc1 = fmaf(pv4, u16f(xp[XW]), oacc1);
                    oacc2 = fmaf(pv4, u16f(xp[2 * XW]), oacc2);
                }
            }
            {
                const int T = tapb + 5;
                if (T < K2) {
                    int kx = kx0 + 5, ky = ky0;
                    if (kx >= KS) { kx -= KS; ++ky; }
                    kb[(size_t)T * PPI] = pv5;
                    const u16* xp = xcb + ((xrb + ky) * 3) * XW + kx;
                    oacc0 = fmaf(pv5, u16f(xp[0]), oacc0);
                    oacc1 = fmaf(pv5, u16f(xp[XW]), oacc1);
                    oacc2 = fmaf(pv5, u16f(xp[2 * XW]), oacc2);
                }
            }
            const int st = (rr & 1) ? 6 : 2;
            tapb += st; kx0 += st;
            if (kx0 >= KS) { kx0 -= KS; ++ky0; }
        }
    }

    // ---- out reduction: 4 waves per px-group via obuf ----
    obuf[(wave * 3 + 0) * 64 + lane] = oacc0;
    obuf[(wave * 3 + 1) * 64 + lane] = oacc1;
    obuf[(wave * 3 + 2) * 64 + lane] = oacc2;
    __syncthreads();
    if (tid < BPX) {
        const int qq = tid >> 6, o = tid & 63;
#pragma unroll
        for (int cch = 0; cch < 3; ++cch) {
            float v = 0.f;
#pragma unroll
            for (int j = 0; j < 4; ++j)
                v += obuf[((4 * qq + j) * 3 + cch) * 64 + o];
            out[((size_t)b * 3 + cch) * PPI + rem0 + tid] = v;
        }
    }
}

// ------------------------------------------------------------ launch -----
extern "C" void kernel_launch(void* const* d_in, const int* in_sizes, int n_in,
                              void* d_out, int out_size, void* d_ws, size_t ws_size,
                              hipStream_t stream)
{
    const float* x     = (const float*)d_in[0];
    const float* z     = (const float*)d_in[1];
    const float* w_in  = (const float*)d_in[2];
    const float* b_in  = (const float*)d_in[3];
    const float* rw1   = (const float*)d_in[4];
    const float* rb1   = (const float*)d_in[5];
    const float* rw2   = (const float*)d_in[6];
    const float* rb2   = (const float*)d_in[7];
    const float* w_out = (const float*)d_in[8];
    const float* b_out = (const float*)d_in[9];

    float* out  = (float*)d_out;
    float* kout = out + (size_t)16 * 3 * PPI;          // kernel output region
    u16*   wsu  = (u16*)d_ws;
    float* bout = (float*)((char*)d_ws + BOUT_BYTE);

    (void)hipFuncSetAttribute((const void*)trunk_kernel,
                              hipFuncAttributeMaxDynamicSharedMemorySize,
                              LDS_TOTAL);

    prep_kernel<<<(69632 + 28672 + 448 + 255) / 256, 256, 0, stream>>>(
        w_in, rw1, rw2, w_out, b_out, wsu, bout);

    trunk_kernel<<<NPIX / BPX, NTH, LDS_TOTAL, stream>>>(
        z, x, b_in, rb1, rb2, wsu, bout, out, kout);
}

// Round 14
// 86.293 us; speedup vs baseline: 1.0340x; 1.0340x over previous
//
#include <hip/hip_runtime.h>
#include <math.h>

#define KS 21
#define K2 441
#define NB 8
#define PPI 4096
#define NPIX 65536
#define STR 72                     // LDS activation row stride (u16)
#define XW 276
#define BPX 256                    // pixels per block (4 low-res rows)
#define NTH 1024                   // 16 waves
#define XROWS 33                   // hi-res rows staged

typedef unsigned short u16;
typedef unsigned int u32;
typedef short short8v __attribute__((ext_vector_type(8)));
typedef float f32x4 __attribute__((ext_vector_type(4)));
typedef float f32x16 __attribute__((ext_vector_type(16)));

// ws layout (u16 units): layer frags 17*4096 | wout frags 28672 | bout 448 f32
#define WOUT_OFF 69632
#define BOUT_BYTE 196608

// dynamic LDS: hbuf 36864 | xs 54656  => 91520 (1 block/CU)
// pass-2 aliases inside the dead hbuf region:
//   pbuf  [64 rows][260 u16] = 33280 B at offset 0
//   sbuf  16*32*4 = 2048 B at offset 33280
//   obuf  16*3*32*4 = 6144 B at offset 0 (after pbuf dead)
#define LDS_XS    36864
#define LDS_TOTAL 91520
#define PB_STRIDE 260

__device__ __forceinline__ u16 f2bf(float x)
{
    union { float f; u32 u; } c; c.f = x;
    u32 r = c.u + 0x7FFF + ((c.u >> 16) & 1);
    return (u16)(r >> 16);
}
__device__ __forceinline__ float bflo(u32 w)
{ union { u32 u; float f; } c; c.u = w << 16; return c.f; }
__device__ __forceinline__ float bfhi(u32 w)
{ union { u32 u; float f; } c; c.u = w & 0xffff0000u; return c.f; }
__device__ __forceinline__ float u16f(u16 h)
{ union { u32 u; float f; } c; c.u = ((u32)h) << 16; return c.f; }

// XCD-aware bijective swizzle (256 blocks): XCD x owns 32 consecutive blocks.
__device__ __forceinline__ int xcd_swz(int i)
{
    return ((i & 7) << 5) | (i >> 3);
}

// ---------------------------------------------------------------- prep ----
__global__ void prep_kernel(const float* __restrict__ w_in,
                            const float* __restrict__ rw1,
                            const float* __restrict__ rw2,
                            const float* __restrict__ w_out,
                            const float* __restrict__ b_out,
                            u16* __restrict__ wsu, float* __restrict__ bout)
{
    int idx = blockIdx.x * 256 + threadIdx.x;
    if (idx < 69632) {
        int u = idx & 4095;
        int j = u & 7, lane = (u >> 3) & 63, frag = (u >> 9) & 7;
        int kk = frag >> 2, nt = frag & 3, layer = idx >> 12;
        int i = kk * 32 + (lane >> 4) * 8 + j;      // K (input ch)
        int o = nt * 16 + (lane & 15);              // N (output ch)
        const float* src;
        if (layer == 0) src = w_in;
        else if (layer & 1) src = rw1 + ((layer - 1) >> 1) * 4096;
        else src = rw2 + ((layer - 2) >> 1) * 4096;
        wsu[idx] = f2bf(src[o * 64 + i]);
    } else if (idx < 69632 + 28672) {
        int u = idx - 69632;
        int j = u & 7, lane = (u >> 3) & 63, t6 = u >> 9;   // 0..55
        int t = t6 % 14, kk = t6 / 14;
        int tap = t * 32 + (lane & 31);
        int i = kk * 16 + (lane >> 5) * 8 + j;
        wsu[idx] = f2bf((tap < K2) ? w_out[tap * 64 + i] : 0.f);
    } else if (idx < 69632 + 28672 + 448) {
        int tap = idx - (69632 + 28672);
        bout[tap] = (tap < K2) ? b_out[tap] : -100.f;
    }
}

// ------------------------------------------------------------- fused -----
__device__ __forceinline__ int reflect256(int v)
{
    v = (v < 0) ? -v : v;
    return (v > 255) ? (510 - v) : v;
}

template <int MODE>
__device__ __forceinline__ void do_layer(u16* hb, const u16* __restrict__ wb,
                                         const float* __restrict__ bias,
                                         float* hreg, int aoff, int wbase,
                                         int c, int g, int lane)
{
    short8v a0 = *(const short8v*)(hb + aoff);
    short8v a1 = *(const short8v*)(hb + aoff + 32);
#pragma unroll
    for (int nt = 0; nt < 4; ++nt) {
        f32x4 acc = {};
        short8v b0 = *(const short8v*)(wb + ((nt)     * 64 + lane) * 8);
        short8v b1 = *(const short8v*)(wb + ((4 + nt) * 64 + lane) * 8);
        acc = __builtin_amdgcn_mfma_f32_16x16x32_bf16(a0, b0, acc, 0, 0, 0);
        acc = __builtin_amdgcn_mfma_f32_16x16x32_bf16(a1, b1, acc, 0, 0, 0);
        const float bv = bias[nt * 16 + c];
#pragma unroll
        for (int r = 0; r < 4; ++r) {
            float v = acc[r] + bv;
            if (MODE == 1) v = fmaxf(v, 0.f);
            if (MODE == 2) { v += hreg[nt * 4 + r]; hreg[nt * 4 + r] = v; }
            if (MODE == 0) hreg[nt * 4 + r] = v;
            hb[(wbase + g * 4 + r) * STR + nt * 16 + c] = f2bf(v);
        }
    }
}

__launch_bounds__(NTH, 1)
__global__ void trunk_kernel(const float* __restrict__ z,
                             const float* __restrict__ x,
                             const float* __restrict__ b_in,
                             const float* __restrict__ rb1,
                             const float* __restrict__ rb2,
                             const u16* __restrict__ wsu,
                             const float* __restrict__ bout,
                             float* __restrict__ out,
                             float* __restrict__ kout)
{
    extern __shared__ __align__(16) char smem[];
    u16*   hbuf = (u16*)(smem);                // [256][STR]
    u16*   xs   = (u16*)(smem + LDS_XS);       // [33][3][XW]
    u16*   pbuf = (u16*)(smem);                // alias: [64][PB_STRIDE]
    float* sbuf = (float*)(smem + 33280);      // [16][32]
    float* obuf = (float*)(smem);              // alias (after pbuf dead)

    const int tid = threadIdx.x, lane = tid & 63, wave = tid >> 6;  // 0..15
    const int pix0 = xcd_swz(blockIdx.x) * BPX;
    const int b = pix0 >> 12, rem0 = pix0 & 4095;
    const int hl0 = rem0 >> 6;

    // ---- stage z -> hbuf (bf16) ----
    {
        const int p = tid & 255, i0 = (tid >> 8) * 16;
        const float* zp = z + ((size_t)b * 64 + i0) * PPI + rem0 + p;
        u32* dst = (u32*)hbuf + p * (STR / 2) + i0 / 2;
#pragma unroll
        for (int i = 0; i < 16; i += 2) {
            float v0 = zp[(size_t)i * PPI];
            float v1 = zp[(size_t)(i + 1) * PPI];
            dst[i / 2] = (u32)f2bf(v0) | ((u32)f2bf(v1) << 16);
        }
    }
    // ---- stage reflected x: rows hl0*4-10 .. hl0*4+22 ----
    for (int u = tid; u < XROWS * 3 * XW; u += NTH) {
        int t = u / XW;
        int j = u - t * XW;
        int rr = t / 3, cch = t - rr * 3;
        int row = reflect256(hl0 * 4 + rr - 10);
        int xcol = reflect256(j - 10);
        xs[u] = f2bf(x[(((size_t)b * 3 + cch) * 256 + row) * 256 + xcol]);
    }
    __syncthreads();

    // ---- 17-layer trunk, wave-private rows [wave*16, wave*16+16) ----
    const int c16 = lane & 15, g4 = lane >> 4;
    const int wbase = wave * 16;
    const int aoff = (wbase + c16) * STR + g4 * 8;
    float hreg[16];

    do_layer<0>(hbuf, wsu, b_in, hreg, aoff, wbase, c16, g4, lane);
#pragma unroll 1
    for (int l = 0; l < NB; ++l) {
        do_layer<1>(hbuf, wsu + (size_t)(1 + 2 * l) * 4096, rb1 + l * 64,
                    hreg, aoff, wbase, c16, g4, lane);
        do_layer<2>(hbuf, wsu + (size_t)(2 + 2 * l) * 4096, rb2 + l * 64,
                    hreg, aoff, wbase, c16, g4, lane);
    }
    __syncthreads();   // all h rows final

    // ---- pass 1 (swapped operands, 32x32x16): e = exp(logit) cached bf16 --
    const int c32 = lane & 31, hi2 = lane >> 5;
    const int wavepx = (wave >> 1) * 32;       // 0..224
    const int par = wave & 1;
    const int tbase = par * 7;

    short8v bh[4];
#pragma unroll
    for (int kk = 0; kk < 4; ++kk)
        bh[kk] = *(const short8v*)(hbuf + (wavepx + c32) * STR + kk * 16 + hi2 * 8);
    __syncthreads();   // hbuf fragment loads complete -> aliases safe

    float ssum = 0.f;
    u32 epack[56];
    const u16* wob = wsu + WOUT_OFF;
#pragma unroll
    for (int ti = 0; ti < 7; ++ti) {
        const int t = tbase + ti;
        f32x16 acc = {};
#pragma unroll
        for (int kk = 0; kk < 4; ++kk) {
            short8v aw = *(const short8v*)(wob + ((kk * 14 + t) * 64 + lane) * 8);
            acc = __builtin_amdgcn_mfma_f32_32x32x16_bf16(aw, bh[kk], acc, 0, 0, 0);
        }
#pragma unroll
        for (int rr = 0; rr < 8; ++rr) {
            const int r0 = 2 * rr;
            const int tap0 = t * 32 + (r0 & 3) + 8 * (r0 >> 2) + 4 * hi2;
            float e0 = __expf(acc[r0] + bout[tap0]);
            float e1 = __expf(acc[r0 + 1] + bout[tap0 + 1]);
            ssum += e0 + e1;
            epack[ti * 8 + rr] = (u32)f2bf(e0) | ((u32)f2bf(e1) << 16);
        }
    }
    ssum += __shfl_xor(ssum, 32);
    if (lane < 32) sbuf[wave * 32 + lane] = ssum;
    __syncthreads();
    const float inv_s = 1.f / (ssum + sbuf[(wave ^ 1) * 32 + c32]);

    // ---- pass 2: apply FMAs + pbuf merge + 1KB instruction-complete stores
    const int pxl = wavepx + c32;
    const int wl = pxl & 63, hlr = pxl >> 6;
    const int xcb = wl * 4;
    float* kb = kout + (size_t)b * K2 * PPI + rem0;
    float oacc0 = 0.f, oacc1 = 0.f, oacc2 = 0.f;
    const int rowbase = par * 32;

#pragma unroll 1
    for (int ti = 0; ti < 7; ++ti) {
        const int t = tbase + ti;
        int tap = t * 32 + 4 * hi2;
        int ky = tap / KS;
        int kx = tap - ky * KS;
#pragma unroll
        for (int rr = 0; rr < 8; ++rr) {
            const u32 ep = epack[ti * 8 + rr];
            float p0 = bflo(ep) * inv_s;
            float p1 = bfhi(ep) * inv_s;
            pbuf[(rowbase + (tap - t * 32)) * PB_STRIDE + pxl] = f2bf(p0);
            if (tap < K2) {
                const u16* xp = xs + ((hlr * 4 + ky) * 3) * XW + xcb + kx;
                oacc0 = fmaf(p0, u16f(xp[0]), oacc0);
                oacc1 = fmaf(p0, u16f(xp[XW]), oacc1);
                oacc2 = fmaf(p0, u16f(xp[2 * XW]), oacc2);
            }
            tap += 1; kx += 1; if (kx >= KS) { kx -= KS; ++ky; }
            pbuf[(rowbase + (tap - t * 32)) * PB_STRIDE + pxl] = f2bf(p1);
            if (tap < K2) {
                const u16* xp = xs + ((hlr * 4 + ky) * 3) * XW + xcb + kx;
                oacc0 = fmaf(p1, u16f(xp[0]), oacc0);
                oacc1 = fmaf(p1, u16f(xp[XW]), oacc1);
                oacc2 = fmaf(p1, u16f(xp[2 * XW]), oacc2);
            }
            const int d = (rr & 1) ? 5 : 1;
            tap += d; kx += d; if (kx >= KS) { kx -= KS; ++ky; }
        }
        __syncthreads();   // pbuf chunk complete
        // cooperative stores: 4 tap-rows per wave, 1KB contiguous each
#pragma unroll
        for (int j = 0; j < 4; ++j) {
            const int row = wave * 4 + j;
            const int T = ((row >> 5) * 7 + ti) * 32 + (row & 31);
            if (T < K2) {
                const u32* pr = (const u32*)(pbuf + row * PB_STRIDE) + lane * 2;
                const u32 w0 = pr[0], w1 = pr[1];
                f32x4 o4 = { bflo(w0), bfhi(w0), bflo(w1), bfhi(w1) };
                *(f32x4*)(kb + (size_t)T * PPI + 4 * lane) = o4;
            }
        }
        __syncthreads();   // stores' pbuf reads done before next overwrite
    }

    // ---- out reduction (obuf aliases dead pbuf) ----
    oacc0 += __shfl_xor(oacc0, 32);
    oacc1 += __shfl_xor(oacc1, 32);
    oacc2 += __shfl_xor(oacc2, 32);
    if (lane < 32) {
        obuf[(wave * 3 + 0) * 32 + lane] = oacc0;
        obuf[(wave * 3 + 1) * 32 + lane] = oacc1;
        obuf[(wave * 3 + 2) * 32 + lane] = oacc2;
    }
    __syncthreads();
    if ((wave & 1) == 0 && lane < 32) {
        const int o = rem0 + wavepx + lane;
#pragma unroll
        for (int cch = 0; cch < 3; ++cch) {
            float v = obuf[(wave * 3 + cch) * 32 + lane] +
                      obuf[((wave + 1) * 3 + cch) * 32 + lane];
            out[((size_t)b * 3 + cch) * PPI + o] = v;
        }
    }
}

// ------------------------------------------------------------ launch -----
extern "C" void kernel_launch(void* const* d_in, const int* in_sizes, int n_in,
                              void* d_out, int out_size, void* d_ws, size_t ws_size,
                              hipStream_t stream)
{
    const float* x     = (const float*)d_in[0];
    const float* z     = (const float*)d_in[1];
    const float* w_in  = (const float*)d_in[2];
    const float* b_in  = (const float*)d_in[3];
    const float* rw1   = (const float*)d_in[4];
    const float* rb1   = (const float*)d_in[5];
    const float* rw2   = (const float*)d_in[6];
    const float* rb2   = (const float*)d_in[7];
    const float* w_out = (const float*)d_in[8];
    const float* b_out = (const float*)d_in[9];

    float* out  = (float*)d_out;
    float* kout = out + (size_t)16 * 3 * PPI;          // kernel output region
    u16*   wsu  = (u16*)d_ws;
    float* bout = (float*)((char*)d_ws + BOUT_BYTE);

    (void)hipFuncSetAttribute((const void*)trunk_kernel,
                              hipFuncAttributeMaxDynamicSharedMemorySize,
                              LDS_TOTAL);

    prep_kernel<<<(69632 + 28672 + 448 + 255) / 256, 256, 0, stream>>>(
        w_in, rw1, rw2, w_out, b_out, wsu, bout);

    trunk_kernel<<<NPIX / BPX, NTH, LDS_TOTAL, stream>>>(
        z, x, b_in, rb1, rb2, wsu, bout, out, kout);
}

// Round 15
// 75.912 us; speedup vs baseline: 1.1754x; 1.1368x over previous
//
#include <hip/hip_runtime.h>
#include <math.h>

#define KS 21
#define K2 441
#define NB 8
#define PPI 4096
#define NPIX 65536
#define STR 72                     // LDS activation row stride (u16)
#define XW 276
#define BPX 256                    // pixels per block
#define NTH 1024                   // 16 waves
#define XROWS 33

typedef unsigned short u16;
typedef unsigned int u32;
typedef short short8v __attribute__((ext_vector_type(8)));
typedef float f32x4 __attribute__((ext_vector_type(4)));
typedef float f32x16 __attribute__((ext_vector_type(16)));

// ws layout (u16 units): layer frags 17*4096 | wout frags 28672 | bout 448 f32
#define WOUT_OFF 69632
#define BOUT_BYTE 196608

// dynamic-LDS byte offsets (16B aligned)
#define LDS_HBUF  0                // 256*72*2      = 36864
#define LDS_XS    36864            // 33*3*276*2    = 54648 (pad->54656)
#define LDS_BSH   91520            // 448*4         = 1792
#define LDS_SBUF  93312            // 16*32*4       = 2048
#define LDS_OBUF  95360            // 16*3*32*4     = 6144
#define LDS_TOTAL 101504

// LDS-only barrier: does NOT drain outstanding global stores (vmcnt),
// unlike __syncthreads() which emits s_waitcnt vmcnt(0) lgkmcnt(0).
// All barriers in this kernel order only LDS data (global loads are
// already ordered before their dependent ds_write by compiler vmcnt waits;
// kout stores need no intra-kernel visibility).
#define BAR_LDS()                                                   \
    do {                                                            \
        asm volatile("s_waitcnt lgkmcnt(0)" ::: "memory");          \
        __builtin_amdgcn_s_barrier();                               \
        __builtin_amdgcn_sched_barrier(0);                          \
    } while (0)

__device__ __forceinline__ u16 f2bf(float x)
{
    union { float f; u32 u; } c; c.f = x;
    u32 r = c.u + 0x7FFF + ((c.u >> 16) & 1);
    return (u16)(r >> 16);
}
__device__ __forceinline__ float bflo(u32 w)
{ union { u32 u; float f; } c; c.u = w << 16; return c.f; }
__device__ __forceinline__ float bfhi(u32 w)
{ union { u32 u; float f; } c; c.u = w & 0xffff0000u; return c.f; }
__device__ __forceinline__ float u16f(u16 h)
{ union { u32 u; float f; } c; c.u = ((u32)h) << 16; return c.f; }

// XCD-aware bijective swizzle (256 blocks): XCD x owns 32 consecutive blocks.
__device__ __forceinline__ int xcd_swz(int i)
{
    return ((i & 7) << 5) | (i >> 3);
}

// ---------------------------------------------------------------- prep ----
__global__ void prep_kernel(const float* __restrict__ w_in,
                            const float* __restrict__ rw1,
                            const float* __restrict__ rw2,
                            const float* __restrict__ w_out,
                            const float* __restrict__ b_out,
                            u16* __restrict__ wsu, float* __restrict__ bout)
{
    int idx = blockIdx.x * 256 + threadIdx.x;
    if (idx < 69632) {
        int u = idx & 4095;
        int j = u & 7, lane = (u >> 3) & 63, frag = (u >> 9) & 7;
        int kk = frag >> 2, nt = frag & 3, layer = idx >> 12;
        int i = kk * 32 + (lane >> 4) * 8 + j;      // K (input ch)
        int o = nt * 16 + (lane & 15);              // N (output ch)
        const float* src;
        if (layer == 0) src = w_in;
        else if (layer & 1) src = rw1 + ((layer - 1) >> 1) * 4096;
        else src = rw2 + ((layer - 2) >> 1) * 4096;
        wsu[idx] = f2bf(src[o * 64 + i]);
    } else if (idx < 69632 + 28672) {
        int u = idx - 69632;
        int j = u & 7, lane = (u >> 3) & 63, t6 = u >> 9;   // 0..55
        int t = t6 % 14, kk = t6 / 14;
        int tap = t * 32 + (lane & 31);
        int i = kk * 16 + (lane >> 5) * 8 + j;
        wsu[idx] = f2bf((tap < K2) ? w_out[tap * 64 + i] : 0.f);
    } else if (idx < 69632 + 28672 + 448) {
        int tap = idx - (69632 + 28672);
        bout[tap] = (tap < K2) ? b_out[tap] : -100.f;
    }
}

// ------------------------------------------------------------- fused -----
__device__ __forceinline__ int reflect256(int v)
{
    v = (v < 0) ? -v : v;
    return (v > 255) ? (510 - v) : v;
}

template <int MODE>
__device__ __forceinline__ void do_layer(u16* hb, const u16* __restrict__ wb,
                                         const float* __restrict__ bias,
                                         float* hreg, int aoff, int wbase,
                                         int c, int g, int lane)
{
    short8v a0 = *(const short8v*)(hb + aoff);
    short8v a1 = *(const short8v*)(hb + aoff + 32);
#pragma unroll
    for (int nt = 0; nt < 4; ++nt) {
        f32x4 acc = {};
        short8v b0 = *(const short8v*)(wb + ((nt)     * 64 + lane) * 8);
        short8v b1 = *(const short8v*)(wb + ((4 + nt) * 64 + lane) * 8);
        acc = __builtin_amdgcn_mfma_f32_16x16x32_bf16(a0, b0, acc, 0, 0, 0);
        acc = __builtin_amdgcn_mfma_f32_16x16x32_bf16(a1, b1, acc, 0, 0, 0);
        const float bv = bias[nt * 16 + c];
#pragma unroll
        for (int r = 0; r < 4; ++r) {
            float v = acc[r] + bv;
            if (MODE == 1) v = fmaxf(v, 0.f);
            if (MODE == 2) { v += hreg[nt * 4 + r]; hreg[nt * 4 + r] = v; }
            if (MODE == 0) hreg[nt * 4 + r] = v;
            hb[(wbase + g * 4 + r) * STR + nt * 16 + c] = f2bf(v);
        }
    }
}

__launch_bounds__(NTH, 1)
__global__ void trunk_kernel(const float* __restrict__ z,
                             const float* __restrict__ x,
                             const float* __restrict__ b_in,
                             const float* __restrict__ rb1,
                             const float* __restrict__ rb2,
                             const u16* __restrict__ wsu,
                             const float* __restrict__ bout,
                             float* __restrict__ out,
                             float* __restrict__ kout)
{
    extern __shared__ __align__(16) char smem[];
    u16*   hbuf = (u16*)(smem + LDS_HBUF);     // [256][STR] in-place acts
    u16*   xs   = (u16*)(smem + LDS_XS);       // [33][3][XW] bf16 x window
    float* bsh  = (float*)(smem + LDS_BSH);    // [448]
    float* sbuf = (float*)(smem + LDS_SBUF);   // [16][32]
    float* obuf = (float*)(smem + LDS_OBUF);   // [16][3][32]

    const int tid = threadIdx.x, lane = tid & 63, wave = tid >> 6;  // 0..15
    const int pix0 = xcd_swz(blockIdx.x) * BPX;
    const int b = pix0 >> 12, rem0 = pix0 & 4095;
    const int hl0 = rem0 >> 6;

    // ---- stage z -> hbuf (bf16) ----
    {
        const int p = tid & 255, i0 = (tid >> 8) * 16;
        const float* zp = z + ((size_t)b * 64 + i0) * PPI + rem0 + p;
        u32* dst = (u32*)hbuf + p * (STR / 2) + i0 / 2;
#pragma unroll
        for (int i = 0; i < 16; i += 2) {
            float v0 = zp[(size_t)i * PPI];
            float v1 = zp[(size_t)(i + 1) * PPI];
            dst[i / 2] = (u32)f2bf(v0) | ((u32)f2bf(v1) << 16);
        }
    }
    // ---- stage reflected x: rows hl0*4-10 .. hl0*4+22 ----
    for (int u = tid; u < XROWS * 3 * XW; u += NTH) {
        int t = u / XW;
        int j = u - t * XW;
        int rr = t / 3, cch = t - rr * 3;
        int row = reflect256(hl0 * 4 + rr - 10);
        int xcol = reflect256(j - 10);
        xs[u] = f2bf(x[(((size_t)b * 3 + cch) * 256 + row) * 256 + xcol]);
    }
    if (tid < 448) bsh[tid] = bout[tid];
    BAR_LDS();

    // ---- 17-layer trunk, wave-private rows [wave*16, wave*16+16) ----
    const int c16 = lane & 15, g4 = lane >> 4;
    const int wbase = wave * 16;
    const int aoff = (wbase + c16) * STR + g4 * 8;
    float hreg[16];

    do_layer<0>(hbuf, wsu, b_in, hreg, aoff, wbase, c16, g4, lane);
#pragma unroll 1
    for (int l = 0; l < NB; ++l) {
        do_layer<1>(hbuf, wsu + (size_t)(1 + 2 * l) * 4096, rb1 + l * 64,
                    hreg, aoff, wbase, c16, g4, lane);
        do_layer<2>(hbuf, wsu + (size_t)(2 + 2 * l) * 4096, rb2 + l * 64,
                    hreg, aoff, wbase, c16, g4, lane);
    }
    BAR_LDS();   // pass 1 reads other waves' h rows (LDS-only ordering)

    // ---- pass 1 (swapped operands, 32x32x16): D[tap][px], px on lane&31 ----
    const int c32 = lane & 31, hi2 = lane >> 5;
    const int wavepx = (wave >> 1) * 32;       // 0..224
    const int tbase = (wave & 1) * 7;          // 7 of 14 tap-tiles

    short8v bh[4];
#pragma unroll
    for (int kk = 0; kk < 4; ++kk)
        bh[kk] = *(const short8v*)(hbuf + (wavepx + c32) * STR + kk * 16 + hi2 * 8);

    float ssum = 0.f;
    u32 epack[56];
    const u16* wob = wsu + WOUT_OFF;
#pragma unroll
    for (int ti = 0; ti < 7; ++ti) {
        const int t = tbase + ti;
        f32x16 acc = {};
#pragma unroll
        for (int kk = 0; kk < 4; ++kk) {
            short8v aw = *(const short8v*)(wob + ((kk * 14 + t) * 64 + lane) * 8);
            acc = __builtin_amdgcn_mfma_f32_32x32x16_bf16(aw, bh[kk], acc, 0, 0, 0);
        }
#pragma unroll
        for (int rr = 0; rr < 8; ++rr) {
            const int r0 = 2 * rr;
            const int tap0 = t * 32 + (r0 & 3) + 8 * (r0 >> 2) + 4 * hi2;
            float e0 = __expf(acc[r0] + bsh[tap0]);
            float e1 = __expf(acc[r0 + 1] + bsh[tap0 + 1]);
            ssum += e0 + e1;
            epack[ti * 8 + rr] = (u32)f2bf(e0) | ((u32)f2bf(e1) << 16);
        }
    }
    ssum += __shfl_xor(ssum, 32);              // combine hi2 tap-halves
    if (lane < 32) sbuf[wave * 32 + lane] = ssum;
    BAR_LDS();
    const float inv_s = 1.f / (ssum + sbuf[(wave ^ 1) * 32 + c32]);

    // ---- pass 2 + fused apply: plain p stores (128B lines) + window FMAs ----
    const int pxl = wavepx + c32;
    const int wl = pxl & 63, hlr = pxl >> 6;
    const int xcb = wl * 4;
    float* kbase = kout + (size_t)b * K2 * PPI + rem0 + pxl;
    float oacc0 = 0.f, oacc1 = 0.f, oacc2 = 0.f;

#pragma unroll
    for (int ti = 0; ti < 7; ++ti) {
        const int t = tbase + ti;
        int tap = t * 32 + 4 * hi2;
        int ky = tap / KS;
        int kx = tap - ky * KS;
#pragma unroll
        for (int rr = 0; rr < 8; ++rr) {
            const u32 ep = epack[ti * 8 + rr];
            float p0 = bflo(ep) * inv_s;
            float p1 = bfhi(ep) * inv_s;
            if (tap < K2) {
                kbase[(size_t)tap * PPI] = p0;
                const u16* xp = xs + ((hlr * 4 + ky) * 3) * XW + xcb + kx;
                oacc0 = fmaf(p0, u16f(xp[0]), oacc0);
                oacc1 = fmaf(p0, u16f(xp[XW]), oacc1);
                oacc2 = fmaf(p0, u16f(xp[2 * XW]), oacc2);
            }
            tap += 1; kx += 1; if (kx >= KS) { kx -= KS; ky += 1; }
            if (tap < K2) {
                kbase[(size_t)tap * PPI] = p1;
                const u16* xp = xs + ((hlr * 4 + ky) * 3) * XW + xcb + kx;
                oacc0 = fmaf(p1, u16f(xp[0]), oacc0);
                oacc1 = fmaf(p1, u16f(xp[XW]), oacc1);
                oacc2 = fmaf(p1, u16f(xp[2 * XW]), oacc2);
            }
            const int d = (rr & 1) ? 5 : 1;    // row-pair walk within C tile
            tap += d; kx += d; if (kx >= KS) { kx -= KS; ky += 1; }
        }
    }

    // ---- out reduction: tap-halves (xor32), then wave-pair via LDS ----
    // BAR_LDS (not __syncthreads): kout stores stay in flight through the
    // epilogue and wave exit; dispatch-end fence handles final visibility.
    oacc0 += __shfl_xor(oacc0, 32);
    oacc1 += __shfl_xor(oacc1, 32);
    oacc2 += __shfl_xor(oacc2, 32);
    if (lane < 32) {
        obuf[(wave * 3 + 0) * 32 + lane] = oacc0;
        obuf[(wave * 3 + 1) * 32 + lane] = oacc1;
        obuf[(wave * 3 + 2) * 32 + lane] = oacc2;
    }
    BAR_LDS();
    if ((wave & 1) == 0 && lane < 32) {
        const int o = rem0 + wavepx + lane;
#pragma unroll
        for (int cch = 0; cch < 3; ++cch) {
            float v = obuf[(wave * 3 + cch) * 32 + lane] +
                      obuf[((wave + 1) * 3 + cch) * 32 + lane];
            out[((size_t)b * 3 + cch) * PPI + o] = v;
        }
    }
}

// ------------------------------------------------------------ launch -----
extern "C" void kernel_launch(void* const* d_in, const int* in_sizes, int n_in,
                              void* d_out, int out_size, void* d_ws, size_t ws_size,
                              hipStream_t stream)
{
    const float* x     = (const float*)d_in[0];
    const float* z     = (const float*)d_in[1];
    const float* w_in  = (const float*)d_in[2];
    const float* b_in  = (const float*)d_in[3];
    const float* rw1   = (const float*)d_in[4];
    const float* rb1   = (const float*)d_in[5];
    const float* rw2   = (const float*)d_in[6];
    const float* rb2   = (const float*)d_in[7];
    const float* w_out = (const float*)d_in[8];
    const float* b_out = (const float*)d_in[9];

    float* out  = (float*)d_out;
    float* kout = out + (size_t)16 * 3 * PPI;          // kernel output region
    u16*   wsu  = (u16*)d_ws;
    float* bout = (float*)((char*)d_ws + BOUT_BYTE);

    (void)hipFuncSetAttribute((const void*)trunk_kernel,
                              hipFuncAttributeMaxDynamicSharedMemorySize,
                              LDS_TOTAL);

    prep_kernel<<<(69632 + 28672 + 448 + 255) / 256, 256, 0, stream>>>(
        w_in, rw1, rw2, w_out, b_out, wsu, bout);

    trunk_kernel<<<NPIX / BPX, NTH, LDS_TOTAL, stream>>>(
        z, x, b_in, rb1, rb2, wsu, bout, out, kout);
}

// Round 16
// 74.678 us; speedup vs baseline: 1.1949x; 1.0165x over previous
//
#include <hip/hip_runtime.h>
#include <math.h>

#define KS 21
#define K2 441
#define NB 8
#define PPI 4096
#define NPIX 65536
#define STR 72                     // LDS activation row stride (u16)
#define XW 276
#define BPX 256                    // pixels per block
#define NTH 1024                   // 16 waves
#define XROWS 33
#define XRS 2208                   // xs4 row stride bytes = 276 * 8

typedef unsigned short u16;
typedef unsigned int u32;
typedef short short8v __attribute__((ext_vector_type(8)));
typedef float f32x4 __attribute__((ext_vector_type(4)));
typedef float f32x16 __attribute__((ext_vector_type(16)));
typedef u32 u32x2v __attribute__((ext_vector_type(2)));

// ws layout (u16 units): layer frags 17*4096 | wout frags 28672 | bout 448 f32
#define WOUT_OFF 69632
#define BOUT_BYTE 196608

// dynamic-LDS byte offsets (16B aligned)
#define LDS_HBUF  0                // 256*72*2        = 36864
#define LDS_XS    36864            // 33*276*8        = 72864 -> ends 109728
#define LDS_BSH   109728           // 448*4           = 1792
#define LDS_SBUF  111520           // 16*32*4         = 2048
#define LDS_OBUF  113568           // 16*3*32*4       = 6144
#define LDS_TOTAL 119712

// LDS-only barrier: does NOT drain outstanding global stores (vmcnt).
#define BAR_LDS()                                                   \
    do {                                                            \
        asm volatile("s_waitcnt lgkmcnt(0)" ::: "memory");          \
        __builtin_amdgcn_s_barrier();                               \
        __builtin_amdgcn_sched_barrier(0);                          \
    } while (0)

__device__ __forceinline__ u16 f2bf(float x)
{
    union { float f; u32 u; } c; c.f = x;
    u32 r = c.u + 0x7FFF + ((c.u >> 16) & 1);
    return (u16)(r >> 16);
}
__device__ __forceinline__ float bflo(u32 w)
{ union { u32 u; float f; } c; c.u = w << 16; return c.f; }
__device__ __forceinline__ float bfhi(u32 w)
{ union { u32 u; float f; } c; c.u = w & 0xffff0000u; return c.f; }

// XCD-aware bijective swizzle (256 blocks): XCD x owns 32 consecutive blocks.
__device__ __forceinline__ int xcd_swz(int i)
{
    return ((i & 7) << 5) | (i >> 3);
}

// xs4 swizzled byte offset for element (row, col): 8B-aligned XOR swizzle
// on addr bits [4:3] -> spreads px-stride-4 reads across 16 banks (<=2-way).
__device__ __forceinline__ u32 xs_off(int row, int col)
{
    u32 off = (u32)row * XRS + (u32)col * 8;
    return off ^ ((((u32)col >> 4) & 3) << 3);
}

// ---------------------------------------------------------------- prep ----
__global__ void prep_kernel(const float* __restrict__ w_in,
                            const float* __restrict__ rw1,
                            const float* __restrict__ rw2,
                            const float* __restrict__ w_out,
                            const float* __restrict__ b_out,
                            u16* __restrict__ wsu, float* __restrict__ bout)
{
    int idx = blockIdx.x * 256 + threadIdx.x;
    if (idx < 69632) {
        int u = idx & 4095;
        int j = u & 7, lane = (u >> 3) & 63, frag = (u >> 9) & 7;
        int kk = frag >> 2, nt = frag & 3, layer = idx >> 12;
        int i = kk * 32 + (lane >> 4) * 8 + j;      // K (input ch)
        int o = nt * 16 + (lane & 15);              // N (output ch)
        const float* src;
        if (layer == 0) src = w_in;
        else if (layer & 1) src = rw1 + ((layer - 1) >> 1) * 4096;
        else src = rw2 + ((layer - 2) >> 1) * 4096;
        wsu[idx] = f2bf(src[o * 64 + i]);
    } else if (idx < 69632 + 28672) {
        int u = idx - 69632;
        int j = u & 7, lane = (u >> 3) & 63, t6 = u >> 9;   // 0..55
        int t = t6 % 14, kk = t6 / 14;
        int tap = t * 32 + (lane & 31);
        int i = kk * 16 + (lane >> 5) * 8 + j;
        wsu[idx] = f2bf((tap < K2) ? w_out[tap * 64 + i] : 0.f);
    } else if (idx < 69632 + 28672 + 448) {
        int tap = idx - (69632 + 28672);
        bout[tap] = (tap < K2) ? b_out[tap] : -100.f;
    }
}

// ------------------------------------------------------------- fused -----
__device__ __forceinline__ int reflect256(int v)
{
    v = (v < 0) ? -v : v;
    return (v > 255) ? (510 - v) : v;
}

template <int MODE>
__device__ __forceinline__ void do_layer(u16* hb, const u16* __restrict__ wb,
                                         const float* __restrict__ bias,
                                         float* hreg, int aoff, int wbase,
                                         int c, int g, int lane)
{
    short8v a0 = *(const short8v*)(hb + aoff);
    short8v a1 = *(const short8v*)(hb + aoff + 32);
#pragma unroll
    for (int nt = 0; nt < 4; ++nt) {
        f32x4 acc = {};
        short8v b0 = *(const short8v*)(wb + ((nt)     * 64 + lane) * 8);
        short8v b1 = *(const short8v*)(wb + ((4 + nt) * 64 + lane) * 8);
        acc = __builtin_amdgcn_mfma_f32_16x16x32_bf16(a0, b0, acc, 0, 0, 0);
        acc = __builtin_amdgcn_mfma_f32_16x16x32_bf16(a1, b1, acc, 0, 0, 0);
        const float bv = bias[nt * 16 + c];
#pragma unroll
        for (int r = 0; r < 4; ++r) {
            float v = acc[r] + bv;
            if (MODE == 1) v = fmaxf(v, 0.f);
            if (MODE == 2) { v += hreg[nt * 4 + r]; hreg[nt * 4 + r] = v; }
            if (MODE == 0) hreg[nt * 4 + r] = v;
            hb[(wbase + g * 4 + r) * STR + nt * 16 + c] = f2bf(v);
        }
    }
}

__launch_bounds__(NTH, 1)
__global__ void trunk_kernel(const float* __restrict__ z,
                             const float* __restrict__ x,
                             const float* __restrict__ b_in,
                             const float* __restrict__ rb1,
                             const float* __restrict__ rb2,
                             const u16* __restrict__ wsu,
                             const float* __restrict__ bout,
                             float* __restrict__ out,
                             float* __restrict__ kout)
{
    extern __shared__ __align__(16) char smem[];
    u16*   hbuf = (u16*)(smem + LDS_HBUF);     // [256][STR] in-place acts
    char*  xsb  = smem + LDS_XS;               // [33][276][4ch u16] swizzled
    float* bsh  = (float*)(smem + LDS_BSH);    // [448]
    float* sbuf = (float*)(smem + LDS_SBUF);   // [16][32]
    float* obuf = (float*)(smem + LDS_OBUF);   // [16][3][32]

    const int tid = threadIdx.x, lane = tid & 63, wave = tid >> 6;  // 0..15
    const int pix0 = xcd_swz(blockIdx.x) * BPX;
    const int b = pix0 >> 12, rem0 = pix0 & 4095;
    const int hl0 = rem0 >> 6;

    // ---- stage z -> hbuf (bf16) ----
    {
        const int p = tid & 255, i0 = (tid >> 8) * 16;
        const float* zp = z + ((size_t)b * 64 + i0) * PPI + rem0 + p;
        u32* dst = (u32*)hbuf + p * (STR / 2) + i0 / 2;
#pragma unroll
        for (int i = 0; i < 16; i += 2) {
            float v0 = zp[(size_t)i * PPI];
            float v1 = zp[(size_t)(i + 1) * PPI];
            dst[i / 2] = (u32)f2bf(v0) | ((u32)f2bf(v1) << 16);
        }
    }
    // ---- stage reflected x: 4ch-packed b64 elements, swizzled ----
    for (int u = tid; u < XROWS * XW; u += NTH) {
        int rr = u / XW, c = u - rr * XW;
        int row = reflect256(hl0 * 4 + rr - 10);
        int xcol = reflect256(c - 10);
        const float* xp = x + (size_t)b * 3 * 65536 + row * 256 + xcol;
        u32 w0 = (u32)f2bf(xp[0]) | ((u32)f2bf(xp[65536]) << 16);
        u32 w1 = (u32)f2bf(xp[2 * 65536]);
        u32x2v wv; wv[0] = w0; wv[1] = w1;
        *(u32x2v*)(xsb + xs_off(rr, c)) = wv;
    }
    if (tid < 448) bsh[tid] = bout[tid];
    BAR_LDS();

    // ---- 17-layer trunk, wave-private rows [wave*16, wave*16+16) ----
    const int c16 = lane & 15, g4 = lane >> 4;
    const int wbase = wave * 16;
    const int aoff = (wbase + c16) * STR + g4 * 8;
    float hreg[16];

    do_layer<0>(hbuf, wsu, b_in, hreg, aoff, wbase, c16, g4, lane);
#pragma unroll 1
    for (int l = 0; l < NB; ++l) {
        do_layer<1>(hbuf, wsu + (size_t)(1 + 2 * l) * 4096, rb1 + l * 64,
                    hreg, aoff, wbase, c16, g4, lane);
        do_layer<2>(hbuf, wsu + (size_t)(2 + 2 * l) * 4096, rb2 + l * 64,
                    hreg, aoff, wbase, c16, g4, lane);
    }
    BAR_LDS();   // pass 1 reads other waves' h rows (LDS-only ordering)

    // ---- pass 1 (swapped operands, 32x32x16): D[tap][px], px on lane&31 ----
    const int c32 = lane & 31, hi2 = lane >> 5;
    const int wavepx = (wave >> 1) * 32;       // 0..224
    const int tbase = (wave & 1) * 7;          // 7 of 14 tap-tiles

    short8v bh[4];
#pragma unroll
    for (int kk = 0; kk < 4; ++kk)
        bh[kk] = *(const short8v*)(hbuf + (wavepx + c32) * STR + kk * 16 + hi2 * 8);

    float ssum = 0.f;
    u32 epack[56];
    const u16* wob = wsu + WOUT_OFF;
#pragma unroll
    for (int ti = 0; ti < 7; ++ti) {
        const int t = tbase + ti;
        f32x16 acc = {};
#pragma unroll
        for (int kk = 0; kk < 4; ++kk) {
            short8v aw = *(const short8v*)(wob + ((kk * 14 + t) * 64 + lane) * 8);
            acc = __builtin_amdgcn_mfma_f32_32x32x16_bf16(aw, bh[kk], acc, 0, 0, 0);
        }
#pragma unroll
        for (int rr = 0; rr < 8; ++rr) {
            const int r0 = 2 * rr;
            const int tap0 = t * 32 + (r0 & 3) + 8 * (r0 >> 2) + 4 * hi2;
            float e0 = __expf(acc[r0] + bsh[tap0]);
            float e1 = __expf(acc[r0 + 1] + bsh[tap0 + 1]);
            ssum += e0 + e1;
            epack[ti * 8 + rr] = (u32)f2bf(e0) | ((u32)f2bf(e1) << 16);
        }
    }
    ssum += __shfl_xor(ssum, 32);              // combine hi2 tap-halves
    if (lane < 32) sbuf[wave * 32 + lane] = ssum;
    BAR_LDS();
    const float inv_s = 1.f / (ssum + sbuf[(wave ^ 1) * 32 + c32]);

    // ---- pass 2 + fused apply: p stores + one ds_read_b64 per tap ----
    const int pxl = wavepx + c32;
    const int wl = pxl & 63, hlr = pxl >> 6;
    const int xcb4 = wl * 4;
    float* kbase = kout + (size_t)b * K2 * PPI + rem0 + pxl;
    float oacc0 = 0.f, oacc1 = 0.f, oacc2 = 0.f;

#pragma unroll
    for (int ti = 0; ti < 7; ++ti) {
        const int t = tbase + ti;
        int tap = t * 32 + 4 * hi2;
        int ky = tap / KS;
        int kx = tap - ky * KS;
#pragma unroll
        for (int rr = 0; rr < 8; ++rr) {
            const u32 ep = epack[ti * 8 + rr];
            float p0 = bflo(ep) * inv_s;
            float p1 = bfhi(ep) * inv_s;
            if (tap < K2) {
                kbase[(size_t)tap * PPI] = p0;
                u32x2v wv = *(const u32x2v*)(xsb + xs_off(hlr * 4 + ky, xcb4 + kx));
                oacc0 = fmaf(p0, bflo(wv[0]), oacc0);
                oacc1 = fmaf(p0, bfhi(wv[0]), oacc1);
                oacc2 = fmaf(p0, bflo(wv[1]), oacc2);
            }
            tap += 1; kx += 1; if (kx >= KS) { kx -= KS; ky += 1; }
            if (tap < K2) {
                kbase[(size_t)tap * PPI] = p1;
                u32x2v wv = *(const u32x2v*)(xsb + xs_off(hlr * 4 + ky, xcb4 + kx));
                oacc0 = fmaf(p1, bflo(wv[0]), oacc0);
                oacc1 = fmaf(p1, bfhi(wv[0]), oacc1);
                oacc2 = fmaf(p1, bflo(wv[1]), oacc2);
            }
            const int d = (rr & 1) ? 5 : 1;    // row-pair walk within C tile
            tap += d; kx += d; if (kx >= KS) { kx -= KS; ky += 1; }
        }
    }

    // ---- out reduction: tap-halves (xor32), then wave-pair via LDS ----
    oacc0 += __shfl_xor(oacc0, 32);
    oacc1 += __shfl_xor(oacc1, 32);
    oacc2 += __shfl_xor(oacc2, 32);
    if (lane < 32) {
        obuf[(wave * 3 + 0) * 32 + lane] = oacc0;
        obuf[(wave * 3 + 1) * 32 + lane] = oacc1;
        obuf[(wave * 3 + 2) * 32 + lane] = oacc2;
    }
    BAR_LDS();
    if ((wave & 1) == 0 && lane < 32) {
        const int o = rem0 + wavepx + lane;
#pragma unroll
        for (int cch = 0; cch < 3; ++cch) {
            float v = obuf[(wave * 3 + cch) * 32 + lane] +
                      obuf[((wave + 1) * 3 + cch) * 32 + lane];
            out[((size_t)b * 3 + cch) * PPI + o] = v;
        }
    }
}

// ------------------------------------------------------------ launch -----
extern "C" void kernel_launch(void* const* d_in, const int* in_sizes, int n_in,
                              void* d_out, int out_size, void* d_ws, size_t ws_size,
                              hipStream_t stream)
{
    const float* x     = (const float*)d_in[0];
    const float* z     = (const float*)d_in[1];
    const float* w_in  = (const float*)d_in[2];
    const float* b_in  = (const float*)d_in[3];
    const float* rw1   = (const float*)d_in[4];
    const float* rb1   = (const float*)d_in[5];
    const float* rw2   = (const float*)d_in[6];
    const float* rb2   = (const float*)d_in[7];
    const float* w_out = (const float*)d_in[8];
    const float* b_out = (const float*)d_in[9];

    float* out  = (float*)d_out;
    float* kout = out + (size_t)16 * 3 * PPI;          // kernel output region
    u16*   wsu  = (u16*)d_ws;
    float* bout = (float*)((char*)d_ws + BOUT_BYTE);

    (void)hipFuncSetAttribute((const void*)trunk_kernel,
                              hipFuncAttributeMaxDynamicSharedMemorySize,
                              LDS_TOTAL);

    prep_kernel<<<(69632 + 28672 + 448 + 255) / 256, 256, 0, stream>>>(
        w_in, rw1, rw2, w_out, b_out, wsu, bout);

    trunk_kernel<<<NPIX / BPX, NTH, LDS_TOTAL, stream>>>(
        z, x, b_in, rb1, rb2, wsu, bout, out, kout);
}